// Round 1
// baseline (87.694 us; speedup 1.0000x reference)
//
#include <hip/hip_runtime.h>
#include <math.h>

// OscillatorBank: B=16, T=500, H=100, HOP=64 -> out [B, T*HOP] f32.
// phase(b, t*64+j, h) = 64*S_{t-1}[b,h] + (j+1)*w[b,t,h],  S = prefix sum of w over t.
// R2: all phase math in REVOLUTIONS (v_sin_f32 takes revolutions -> kills the 1/2pi mul),
//     staging buffer interleaved float2 {w_rev, base_rev}, synth packs {w,base,c} into one
//     float4 LDS slot (1x ds_read_b128 per harmonic instead of 3x ds_read_b32),
//     4 hops per 256-thread block.

#define OB_B 16
#define OB_T 500
#define OB_H 100
#define OB_HOP 64

constexpr double SR_D = 44100.0;

// Kernel 1: one wave per (b,h). Lane l handles t in [8l, 8l+8).
// w_rev = h^(1+stretch)*f0 / SR  (revolutions per sample), computed in double
// (exp2 with wave-uniform log2(h)). Wave-scan of chunk sums -> exclusive prefix S.
// Writes float2 {w_rev, frac(64*S)} at [b,t,h] (interleaved).
__global__ void __launch_bounds__(256)
ob_scan_fused(const float* __restrict__ f0,
              const float* __restrict__ stretch,
              float2* __restrict__ wb)
{
    int wave = threadIdx.x >> 6;
    int lane = threadIdx.x & 63;
    int bh   = blockIdx.x * 4 + wave;      // 0..1599
    int b = bh / OB_H, h = bh % OB_H;
    double L = log2((double)(h + 1));      // wave-uniform
    const float* f0b = f0      + b * OB_T;
    const float* stb = stretch + b * OB_T;

    double w[8];
    double csum = 0.0;
    int t0 = lane * 8;
    #pragma unroll
    for (int k = 0; k < 8; ++k) {
        int t = t0 + k;
        double wv = 0.0;
        if (t < OB_T) {
            double harm = exp2((1.0 + (double)stb[t]) * L) * (double)f0b[t]; // Hz
            wv = harm * (1.0 / SR_D);      // revolutions per sample
        }
        w[k] = wv;
        csum += wv;
    }
    // inclusive wave scan of chunk sums (double shuffles)
    double incl = csum;
    #pragma unroll
    for (int off = 1; off < 64; off <<= 1) {
        double up = __shfl_up(incl, (unsigned)off, 64);
        if (lane >= off) incl += up;
    }
    double S = incl - csum;                // exclusive prefix: sum of w for t < t0
    size_t rowbase = (size_t)b * OB_T * OB_H + h;
    #pragma unroll
    for (int k = 0; k < 8; ++k) {
        int t = t0 + k;
        if (t < OB_T) {
            double ph = 64.0 * S;          // revolutions
            ph -= trunc(ph);               // frac -> [0,1); off-by-period harmless (periodic)
            wb[rowbase + (size_t)t * OB_H] = make_float2((float)w[k], (float)ph);
            S += w[k];
        }
    }
}

// Kernel 2: 4 hops per 256-thread block; wave w owns hop bt = blockIdx*4+w,
// thread j = sample in hop. Inner loop: one ds_read_b128 {w,base,c} per harmonic,
// ph_rev = base + (j+1)*w, s += c * v_sin_f32(ph_rev).
__global__ void __launch_bounds__(256)
ob_synth(const float2* __restrict__ wb,
         const float* __restrict__ amps,
         const float* __restrict__ loud,
         float* __restrict__ out)
{
    int wave = threadIdx.x >> 6;
    int j    = threadIdx.x & 63;
    int bt   = blockIdx.x * 4 + wave;      // b*T + t, 0..7999
    __shared__ float4 s4[4][OB_H];
    size_t row = (size_t)bt * OB_H;
    float ld = loud[bt] * (1.0f / OB_H);
    for (int i = j; i < OB_H; i += 64) {
        float2 v = wb[row + i];
        // w_rev > 0.5 <=> harmonic freq > nyquist -> masked amplitude
        float c = (v.x > 0.5f) ? 0.0f : ld * amps[row + i];
        s4[wave][i] = make_float4(v.x, v.y, c, 0.0f);
    }
    __syncthreads();
    float jf = (float)(j + 1);
    float s = 0.0f;
    #pragma unroll
    for (int h = 0; h < OB_H; ++h) {
        float4 v = s4[wave][h];
        // v_sin_f32: input in revolutions; |arg| <= ~15.5 rev, well within HW range
        s += v.z * __builtin_amdgcn_sinf(v.y + jf * v.x);
    }
    out[(size_t)bt * OB_HOP + j] = s;
}

extern "C" void kernel_launch(void* const* d_in, const int* in_sizes, int n_in,
                              void* d_out, int out_size, void* d_ws, size_t ws_size,
                              hipStream_t stream)
{
    const float* f0      = (const float*)d_in[0];
    const float* loud    = (const float*)d_in[1];
    const float* amps    = (const float*)d_in[2];
    const float* stretch = (const float*)d_in[3];

    float2* wb  = (float2*)d_ws;           // 16*500*100 * 8 B = 6.4 MB
    float*  out = (float*)d_out;

    ob_scan_fused<<<(OB_B * OB_H) / 4, 256, 0, stream>>>(f0, stretch, wb);
    ob_synth<<<(OB_B * OB_T) / 4, 256, 0, stream>>>(wb, amps, loud, out);
}